// Round 8
// baseline (442.380 us; speedup 1.0000x reference)
//
#include <hip/hip_runtime.h>
#include <hip/hip_bf16.h>

// Problem constants: B=8,N=64,T=128,E=128,H=8,R=4,DH=16
constexpr int cE  = 128;
constexpr int cR  = 4;
constexpr int cNT = 65536;   // B*N*T tokens

typedef short s8v  __attribute__((ext_vector_type(8)));   // 8 bf16 MFMA frag
typedef float f4v  __attribute__((ext_vector_type(4)));   // MFMA accumulator

static __device__ __forceinline__ unsigned short f2bf(float x) {
    union { float f; unsigned int u; } v; v.f = x;
    unsigned int r = v.u + 0x7fffu + ((v.u >> 16) & 1u);  // RNE
    return (unsigned short)(r >> 16);
}

// quad_perm broadcast: every aligned 4-lane group reads its lane C (ctrl = C*0x55)
#define QB(x, C) __int_as_float(__builtin_amdgcn_update_dpp( \
            0, __float_as_int(x), C, 0xF, 0xF, false))

// ---------------------------------------------------------------------------
// Prolog (merged weights+biases), quad-split (r5). Unchanged.
// ---------------------------------------------------------------------------
__global__ __launch_bounds__(256) void k_prep(
    const float* __restrict__ Wq, const float* __restrict__ Wk, const float* __restrict__ Wv,
    const float* __restrict__ in_w, const float* __restrict__ out_w, const float* __restrict__ fc_w,
    const float* __restrict__ bq, const float* __restrict__ bk, const float* __restrict__ bv,
    const float* __restrict__ in_b, const float* __restrict__ out_b, const float* __restrict__ fc_b,
    unsigned short* __restrict__ wqkv, unsigned short* __restrict__ meff,
    float* __restrict__ bqkv, float* __restrict__ beff)
{
    int bid = blockIdx.x;
    if (bid < 1792) {
        int gt = bid * 256 + (int)threadIdx.x;
        int o  = gt >> 2;
        int p  = gt & 3;
        float s;
        if (o < 3 * cE * cE) {
            int w   = o >> 14;
            int rem = o & (cE * cE - 1);
            int f = rem >> 7, g = rem & 127;
            const float* Wsel = (w == 0) ? Wq : ((w == 1) ? Wk : Wv);
            const float* iw = in_w + (size_t)(w * cE + f) * cE + p * 32;
            const float* wp = Wsel + (size_t)(p * 32) * cE + g;
            float s0 = 0.f, s1 = 0.f;
            #pragma unroll
            for (int e = 0; e < 32; e += 2) {
                s0 += iw[e]     * wp[(size_t)e * cE];
                s1 += iw[e + 1] * wp[(size_t)(e + 1) * cE];
            }
            s = s0 + s1;
            s += __shfl_xor(s, 1);
            s += __shfl_xor(s, 2);
            if (w == 0) s *= 0.25f;                // 1/sqrt(DH) folded into q-path
            if (p == 0) wqkv[o] = f2bf(s);
        } else {
            int i2 = o - 3 * cE * cE;
            int e1 = i2 >> 9;
            int c  = i2 & 511;
            const float* fw = fc_w + (size_t)e1 * 512 + (c >> 7) * cE + p * 32;
            int ee = c & 127;
            const float* ow = out_w + (size_t)(p * 32) * cE + ee;
            float s0 = 0.f, s1 = 0.f;
            #pragma unroll
            for (int ff = 0; ff < 32; ff += 2) {
                s0 += fw[ff]     * ow[(size_t)ff * cE];
                s1 += fw[ff + 1] * ow[(size_t)(ff + 1) * cE];
            }
            s = s0 + s1;
            s += __shfl_xor(s, 1);
            s += __shfl_xor(s, 2);
            if (p == 0) meff[i2] = f2bf(s);
        }
    } else {
        int idx = (bid - 1792) * 256 + (int)threadIdx.x;   // 0..511
        if (idx < 384) {
            int w = idx >> 7, f = idx & 127;
            const float* bsel = (w == 0) ? bq : ((w == 1) ? bk : bv);
            const float* iw = in_w + (size_t)(w * cE + f) * cE;
            float s = 0.f;
            for (int e = 0; e < cE; ++e) s += iw[e] * bsel[e];
            s += in_b[w * cE + f];
            if (w == 0) s *= 0.25f;
            bqkv[idx] = s;
        } else {
            int f = idx - 384;
            float s = 0.f;
            for (int c = 0; c < 512; ++c) s += fc_w[(size_t)f * 512 + c] * out_b[c & 127];
            beff[f] = s + fc_b[f];
        }
    }
}

// ---------------------------------------------------------------------------
// r12: ABLATION AT THE r11 SHAPE. Production = k_abl<4,1> == r11 exactly
// (162us, best). Diagnostics (2 reps each, rep-shifted blocks, keep-alive
// per rule #17):
//   k_abl<1,2> = stage+barriers only     -> PH1
//   k_abl<2,2> = stage+QKV+bias          -> PH2 (QKV path = PH2-PH1)
// Channels: top-5 rows = slowest k_abl variant (VGPR distinguishes);
// headline ~= 327 + 2*PH1 + 2*PH2.
// Pre-committed: PH1>=50 -> r13 pre-converts inputs to bf16 combined layout
// (separate pass) + global_load_lds staging. PH2-PH1>=50 -> r13 hoists the
// per-wave wqkv frags into registers across chunks. Else -> split back half.
// ---------------------------------------------------------------------------
#define TOKB   64    // tokens per block  (grid 1024)
#define TOKC   16    // tokens per chunk
#define PITCH  136   // bf16 elems; row stride 272B: 16B-aligned, 4-bank rotation
#define OPITCH 520   // bf16 elems; row stride 1040B: 16B-aligned, 4-bank rotation

template<int PH, int REPS>
__global__ __launch_bounds__(512) void k_abl(
    const float* __restrict__ node, const float* __restrict__ sub,
    const unsigned short* __restrict__ wqkv,   // [3][128][128] bf16 (B^T layout)
    const unsigned short* __restrict__ meff,   // [128][512]    bf16 (B^T layout)
    const float* __restrict__ bqkv,            // [3*128]
    const float* __restrict__ beff,            // [128]
    float* __restrict__ out)                   // [NT][128]
{
    __shared__ unsigned short sA[64 * PITCH];   // 17408 B staging (16 tok x 4 r)
    __shared__ unsigned short sO[16 * OPITCH];  // 16640 B attn output

    const int tid  = threadIdx.x;
    const int lane = tid & 63;
    const int wv   = tid >> 6;      // wave 0..7 -> owns head wv
    const int l15  = lane & 15;
    const int lq   = lane >> 4;     // quad 0..3 (k/d sub-range owner)

    const int stok = tid >> 5;      // staging token 0..15
    const int seg  = tid & 31;      // staging e-group of 4
    const int e0   = seg * 4;

    #pragma clang loop unroll(disable)
    for (int rep = 0; rep < REPS; ++rep) {
        // rep-shifted block -> re-reads other blocks' tokens (L2/L3-cold-ish)
        const int tokBlock = ((((int)blockIdx.x) + rep * 331) & 1023) * TOKB;

        #pragma clang loop unroll(disable)
        for (int chunk = 0; chunk < TOKB / TOKC; ++chunk) {
            const int tokBase = tokBlock + chunk * TOKC;
            __syncthreads();   // prev chunk's sA/sO readers done

            // ---- stage combined -> sA (bf16), vectorized
            {
                const float* np = node + (size_t)(tokBase + stok) * cE + e0;
                const float* sp = sub  + (size_t)(tokBase + stok) * 384 + seg * 12;
                float4 vn = *(const float4*)np;
                float4 f0 = *(const float4*)(sp + 0);   // e0j0 e0j1 e0j2 e1j0
                float4 f1 = *(const float4*)(sp + 4);   // e1j1 e1j2 e2j0 e2j1
                float4 f2 = *(const float4*)(sp + 8);   // e2j2 e3j0 e3j1 e3j2
                *(ushort4*)&sA[(stok * cR) * PITCH + e0] =
                    make_ushort4(f2bf(vn.x), f2bf(vn.y), f2bf(vn.z), f2bf(vn.w));
                *(ushort4*)&sA[(stok * cR + 1) * PITCH + e0] =
                    make_ushort4(f2bf(f0.x), f2bf(f0.w), f2bf(f1.z), f2bf(f2.y));
                *(ushort4*)&sA[(stok * cR + 2) * PITCH + e0] =
                    make_ushort4(f2bf(f0.y), f2bf(f1.x), f2bf(f1.w), f2bf(f2.z));
                *(ushort4*)&sA[(stok * cR + 3) * PITCH + e0] =
                    make_ushort4(f2bf(f0.z), f2bf(f1.y), f2bf(f2.x), f2bf(f2.w));
            }
            __syncthreads();

            if constexpr (PH == 1) {
                // keep staged tile live; skip all downstream phases
                int4 v = *(const int4*)&sA[(tid & 63) * PITCH + ((tid >> 6) & 7) * 8];
                int keep = v.x + v.y + v.z + v.w;
                asm volatile("" :: "v"(keep));
                continue;
            } else {

            // ---- QKV GEMM: [64 rows x 16 f] per wave (head wv), 3 weights.
            f4v qa[4], ka[4], va[4];
            #pragma unroll
            for (int rt = 0; rt < 4; ++rt) {
                qa[rt] = (f4v){0.f, 0.f, 0.f, 0.f};
                ka[rt] = (f4v){0.f, 0.f, 0.f, 0.f};
                va[rt] = (f4v){0.f, 0.f, 0.f, 0.f};
            }
            #pragma unroll
            for (int kc = 0; kc < 4; ++kc) {
                const int koff = kc * 32 + lq * 8;
                s8v a0 = *(const s8v*)&sA[(0 * 16 + l15) * PITCH + koff];
                s8v a1 = *(const s8v*)&sA[(1 * 16 + l15) * PITCH + koff];
                s8v a2 = *(const s8v*)&sA[(2 * 16 + l15) * PITCH + koff];
                s8v a3 = *(const s8v*)&sA[(3 * 16 + l15) * PITCH + koff];
                const size_t fo = (size_t)(wv * 16 + l15) * cE + koff;
                s8v wq_ = *(const s8v*)(wqkv + fo);
                s8v wk_ = *(const s8v*)(wqkv + 16384 + fo);
                s8v wv_ = *(const s8v*)(wqkv + 32768 + fo);
                qa[0] = __builtin_amdgcn_mfma_f32_16x16x32_bf16(wq_, a0, qa[0], 0, 0, 0);
                qa[1] = __builtin_amdgcn_mfma_f32_16x16x32_bf16(wq_, a1, qa[1], 0, 0, 0);
                qa[2] = __builtin_amdgcn_mfma_f32_16x16x32_bf16(wq_, a2, qa[2], 0, 0, 0);
                qa[3] = __builtin_amdgcn_mfma_f32_16x16x32_bf16(wq_, a3, qa[3], 0, 0, 0);
                ka[0] = __builtin_amdgcn_mfma_f32_16x16x32_bf16(wk_, a0, ka[0], 0, 0, 0);
                ka[1] = __builtin_amdgcn_mfma_f32_16x16x32_bf16(wk_, a1, ka[1], 0, 0, 0);
                ka[2] = __builtin_amdgcn_mfma_f32_16x16x32_bf16(wk_, a2, ka[2], 0, 0, 0);
                ka[3] = __builtin_amdgcn_mfma_f32_16x16x32_bf16(wk_, a3, ka[3], 0, 0, 0);
                va[0] = __builtin_amdgcn_mfma_f32_16x16x32_bf16(wv_, a0, va[0], 0, 0, 0);
                va[1] = __builtin_amdgcn_mfma_f32_16x16x32_bf16(wv_, a1, va[1], 0, 0, 0);
                va[2] = __builtin_amdgcn_mfma_f32_16x16x32_bf16(wv_, a2, va[2], 0, 0, 0);
                va[3] = __builtin_amdgcn_mfma_f32_16x16x32_bf16(wv_, a3, va[3], 0, 0, 0);
            }
            // bias add (L1/L2-resident global reads)
            {
                const int fb = wv * 16 + lq * 4;
                float4 b0 = *(const float4*)(bqkv + fb);
                float4 b1 = *(const float4*)(bqkv + cE + fb);
                float4 b2 = *(const float4*)(bqkv + 2 * cE + fb);
                #pragma unroll
                for (int rt = 0; rt < 4; ++rt) {
                    qa[rt][0] += b0.x; qa[rt][1] += b0.y;
                    qa[rt][2] += b0.z; qa[rt][3] += b0.w;
                    ka[rt][0] += b1.x; ka[rt][1] += b1.y;
                    ka[rt][2] += b1.z; ka[rt][3] += b1.w;
                    va[rt][0] += b2.x; va[rt][1] += b2.y;
                    va[rt][2] += b2.z; va[rt][3] += b2.w;
                }
            }

            if constexpr (PH == 2) {
                // keep all QKV accumulators live; skip attention+final
                float keep = 0.f;
                #pragma unroll
                for (int rt = 0; rt < 4; ++rt)
                    #pragma unroll
                    for (int i = 0; i < 4; ++i)
                        keep += qa[rt][i] + ka[rt][i] + va[rt][i];
                asm volatile("" :: "v"(keep));
                continue;
            } else {

            // ---- attention in registers -> sO
            {
                const int r  = l15 & 3;
                const int tq = l15 >> 2;
                #pragma unroll
                for (int rt = 0; rt < 4; ++rt) {
                    f4v q = qa[rt], k = ka[rt], v = va[rt];
                    float s0 = QB(k[0],0x00)*q[0] + QB(k[1],0x00)*q[1]
                             + QB(k[2],0x00)*q[2] + QB(k[3],0x00)*q[3];
                    float s1 = QB(k[0],0x55)*q[0] + QB(k[1],0x55)*q[1]
                             + QB(k[2],0x55)*q[2] + QB(k[3],0x55)*q[3];
                    float s2 = QB(k[0],0xAA)*q[0] + QB(k[1],0xAA)*q[1]
                             + QB(k[2],0xAA)*q[2] + QB(k[3],0xAA)*q[3];
                    float s3 = QB(k[0],0xFF)*q[0] + QB(k[1],0xFF)*q[1]
                             + QB(k[2],0xFF)*q[2] + QB(k[3],0xFF)*q[3];
                    s0 += __shfl_xor(s0, 16); s0 += __shfl_xor(s0, 32);
                    s1 += __shfl_xor(s1, 16); s1 += __shfl_xor(s1, 32);
                    s2 += __shfl_xor(s2, 16); s2 += __shfl_xor(s2, 32);
                    s3 += __shfl_xor(s3, 16); s3 += __shfl_xor(s3, 32);
                    float m = fmaxf(fmaxf(s0, s1), fmaxf(s2, s3));
                    float p0 = __expf(s0 - m), p1 = __expf(s1 - m);
                    float p2 = __expf(s2 - m), p3 = __expf(s3 - m);
                    float inv = 1.f / (p0 + p1 + p2 + p3);
                    p0 *= inv; p1 *= inv; p2 *= inv; p3 *= inv;
                    float o0 = p0*QB(v[0],0x00) + p1*QB(v[0],0x55)
                             + p2*QB(v[0],0xAA) + p3*QB(v[0],0xFF);
                    float o1 = p0*QB(v[1],0x00) + p1*QB(v[1],0x55)
                             + p2*QB(v[1],0xAA) + p3*QB(v[1],0xFF);
                    float o2 = p0*QB(v[2],0x00) + p1*QB(v[2],0x55)
                             + p2*QB(v[2],0xAA) + p3*QB(v[2],0xFF);
                    float o3 = p0*QB(v[3],0x00) + p1*QB(v[3],0x55)
                             + p2*QB(v[3],0xAA) + p3*QB(v[3],0xFF);
                    int tok = rt * 4 + tq;
                    *(ushort4*)&sO[tok * OPITCH + r * cE + wv * 16 + lq * 4] =
                        make_ushort4(f2bf(o0), f2bf(o1), f2bf(o2), f2bf(o3));
                }
            }
            __syncthreads();   // sO ready

            // ---- final GEMM: [16 tok x 128] = sO[16x512] @ Meff^T.
            {
                f4v acc = (f4v){0.f, 0.f, 0.f, 0.f};
                #pragma unroll 4
                for (int kc = 0; kc < 16; ++kc) {
                    int koff = kc * 32 + lq * 8;
                    s8v a = *(const s8v*)&sO[l15 * OPITCH + koff];
                    s8v b = *(const s8v*)(meff + (size_t)(wv * 16 + l15) * 512 + koff);
                    acc = __builtin_amdgcn_mfma_f32_16x16x32_bf16(b, a, acc, 0, 0, 0);
                }
                const int col = wv * 16 + lq * 4;
                float4 b4 = *(const float4*)&beff[col];
                *(float4*)&out[(size_t)(tokBase + l15) * cE + col] =
                    make_float4(acc[0] + b4.x, acc[1] + b4.y,
                                acc[2] + b4.z, acc[3] + b4.w);
            }
            } // PH==2 else
            } // PH==1 else
        }
    }
}

// ---------------------------------------------------------------------------
extern "C" void kernel_launch(void* const* d_in, const int* in_sizes, int n_in,
                              void* d_out, int out_size, void* d_ws, size_t ws_size,
                              hipStream_t stream) {
    const float* node  = (const float*)d_in[0];
    const float* sub   = (const float*)d_in[1];
    const float* Wq    = (const float*)d_in[2];
    const float* bq    = (const float*)d_in[3];
    const float* Wk    = (const float*)d_in[4];
    const float* bk    = (const float*)d_in[5];
    const float* Wv    = (const float*)d_in[6];
    const float* bv    = (const float*)d_in[7];
    const float* in_w  = (const float*)d_in[8];
    const float* in_b  = (const float*)d_in[9];
    const float* out_w = (const float*)d_in[10];
    const float* out_b = (const float*)d_in[11];
    const float* fc_w  = (const float*)d_in[12];
    const float* fc_b  = (const float*)d_in[13];

    unsigned short* ws_wqkv = (unsigned short*)d_ws;                 // 3*128*128 bf16
    unsigned short* ws_meff = ws_wqkv + 3 * cE * cE;                 // 128*512  bf16
    float* ws_bqkv = (float*)((char*)d_ws + (size_t)(3 * cE * cE + cE * cR * cE) * 2);
    float* ws_beff = ws_bqkv + 3 * cE;

    k_prep<<<dim3(1794), dim3(256), 0, stream>>>(Wq, Wk, Wv, in_w, out_w, fc_w,
                                                 bq, bk, bv, in_b, out_b, fc_b,
                                                 ws_wqkv, ws_meff, ws_bqkv, ws_beff);
    // production: r11 structure exactly (PH=4, 1 rep)
    k_abl<4, 1><<<dim3(cNT / TOKB), dim3(512), 0, stream>>>(
        node, sub, ws_wqkv, ws_meff, ws_bqkv, ws_beff, (float*)d_out);
    // diagnostic A: stage+QKV+bias only (front half), 2 reps
    k_abl<2, 2><<<dim3(cNT / TOKB), dim3(512), 0, stream>>>(
        node, sub, ws_wqkv, ws_meff, ws_bqkv, ws_beff, (float*)d_out);
    // diagnostic B: stage only, 2 reps
    k_abl<1, 2><<<dim3(cNT / TOKB), dim3(512), 0, stream>>>(
        node, sub, ws_wqkv, ws_meff, ws_bqkv, ws_beff, (float*)d_out);
}

// Round 9
// 302.428 us; speedup vs baseline: 1.4628x; 1.4628x over previous
//
#include <hip/hip_runtime.h>
#include <hip/hip_bf16.h>

// Problem constants: B=8,N=64,T=128,E=128,H=8,R=4,DH=16
constexpr int cE  = 128;
constexpr int cR  = 4;
constexpr int cNT = 65536;   // B*N*T tokens

typedef short s8v  __attribute__((ext_vector_type(8)));   // 8 bf16 MFMA frag
typedef float f4v  __attribute__((ext_vector_type(4)));   // MFMA accumulator

static __device__ __forceinline__ unsigned short f2bf(float x) {
    union { float f; unsigned int u; } v; v.f = x;
    unsigned int r = v.u + 0x7fffu + ((v.u >> 16) & 1u);  // RNE
    return (unsigned short)(r >> 16);
}

// quad_perm broadcast: every aligned 4-lane group reads its lane C (ctrl = C*0x55)
#define QB(x, C) __int_as_float(__builtin_amdgcn_update_dpp( \
            0, __float_as_int(x), C, 0xF, 0xF, false))

// ---------------------------------------------------------------------------
// Prolog (merged weights+biases), quad-split (r5). Unchanged.
// ---------------------------------------------------------------------------
__global__ __launch_bounds__(256) void k_prep(
    const float* __restrict__ Wq, const float* __restrict__ Wk, const float* __restrict__ Wv,
    const float* __restrict__ in_w, const float* __restrict__ out_w, const float* __restrict__ fc_w,
    const float* __restrict__ bq, const float* __restrict__ bk, const float* __restrict__ bv,
    const float* __restrict__ in_b, const float* __restrict__ out_b, const float* __restrict__ fc_b,
    unsigned short* __restrict__ wqkv, unsigned short* __restrict__ meff,
    float* __restrict__ bqkv, float* __restrict__ beff)
{
    int bid = blockIdx.x;
    if (bid < 1792) {
        int gt = bid * 256 + (int)threadIdx.x;
        int o  = gt >> 2;
        int p  = gt & 3;
        float s;
        if (o < 3 * cE * cE) {
            int w   = o >> 14;
            int rem = o & (cE * cE - 1);
            int f = rem >> 7, g = rem & 127;
            const float* Wsel = (w == 0) ? Wq : ((w == 1) ? Wk : Wv);
            const float* iw = in_w + (size_t)(w * cE + f) * cE + p * 32;
            const float* wp = Wsel + (size_t)(p * 32) * cE + g;
            float s0 = 0.f, s1 = 0.f;
            #pragma unroll
            for (int e = 0; e < 32; e += 2) {
                s0 += iw[e]     * wp[(size_t)e * cE];
                s1 += iw[e + 1] * wp[(size_t)(e + 1) * cE];
            }
            s = s0 + s1;
            s += __shfl_xor(s, 1);
            s += __shfl_xor(s, 2);
            if (w == 0) s *= 0.25f;                // 1/sqrt(DH) folded into q-path
            if (p == 0) wqkv[o] = f2bf(s);
        } else {
            int i2 = o - 3 * cE * cE;
            int e1 = i2 >> 9;
            int c  = i2 & 511;
            const float* fw = fc_w + (size_t)e1 * 512 + (c >> 7) * cE + p * 32;
            int ee = c & 127;
            const float* ow = out_w + (size_t)(p * 32) * cE + ee;
            float s0 = 0.f, s1 = 0.f;
            #pragma unroll
            for (int ff = 0; ff < 32; ff += 2) {
                s0 += fw[ff]     * ow[(size_t)ff * cE];
                s1 += fw[ff + 1] * ow[(size_t)(ff + 1) * cE];
            }
            s = s0 + s1;
            s += __shfl_xor(s, 1);
            s += __shfl_xor(s, 2);
            if (p == 0) meff[i2] = f2bf(s);
        }
    } else {
        int idx = (bid - 1792) * 256 + (int)threadIdx.x;   // 0..511
        if (idx < 384) {
            int w = idx >> 7, f = idx & 127;
            const float* bsel = (w == 0) ? bq : ((w == 1) ? bk : bv);
            const float* iw = in_w + (size_t)(w * cE + f) * cE;
            float s = 0.f;
            for (int e = 0; e < cE; ++e) s += iw[e] * bsel[e];
            s += in_b[w * cE + f];
            if (w == 0) s *= 0.25f;
            bqkv[idx] = s;
        } else {
            int f = idx - 384;
            float s = 0.f;
            for (int c = 0; c < 512; ++c) s += fc_w[(size_t)f * 512 + c] * out_b[c & 127];
            beff[f] = s + fc_b[f];
        }
    }
}

// ---------------------------------------------------------------------------
// r13: TWO-KERNEL SPLIT. r12 ablation: front (stage+QKV) <= ~57us/pass, so
// back half (attention+final GEMM) >= 105us of 163. The final GEMM re-reads
// the full 128KB meff from L2 once per 16-token chunk-instance (4096x =
// ~920MB of L2 weight traffic at ~200cy latency, ~1 resident block/CU).
// Split: kernel A = stage+QKV+attention -> oconcat[NT][512] bf16 (64MB,
// LLC-resident); kernel B = dedicated streaming GEMM out = oconcat@meff^T
// with 64-token tiles (meff read once per 64 tokens: 4x less weight
// traffic, canonical pipelined GEMM, high TLP).
// A also drops to TOKB=16 single-chunk blocks (grid 4096): fewer barriers
// (1/block), more independent blocks; TOKC=16 weight amortization retained
// (r9's regression was TOKC=8, not block count).
// This round doubles as the back-half split measurement: A's dur = 163 -
// (final GEMM share) + O-write cost.
// Fallback: if ws_size < 66MB, launch the r11 monolith (k_mainR11).
// ---------------------------------------------------------------------------
#define TOKC   16    // tokens per block (kernel A)
#define PITCH  136   // bf16 elems; row stride 272B: 16B-aligned, 4-bank rotation
#define OPITCH 520   // r11 fallback only

__global__ __launch_bounds__(512) void k_mainA(
    const float* __restrict__ node, const float* __restrict__ sub,
    const unsigned short* __restrict__ wqkv,   // [3][128][128] bf16 (B^T layout)
    const float* __restrict__ bqkv,            // [3*128]
    unsigned short* __restrict__ oconcat)      // [NT][512] bf16
{
    __shared__ unsigned short sA[64 * PITCH];   // 17408 B staging (16 tok x 4 r)

    const int tid  = threadIdx.x;
    const int lane = tid & 63;
    const int wv   = tid >> 6;      // wave 0..7 -> owns head wv
    const int l15  = lane & 15;
    const int lq   = lane >> 4;     // quad 0..3 (k/d sub-range owner)

    const int tokBase = blockIdx.x * TOKC;
    const int stok = tid >> 5;      // staging token 0..15
    const int seg  = tid & 31;      // staging e-group of 4
    const int e0   = seg * 4;

    // ---- stage combined -> sA (bf16), vectorized
    {
        const float* np = node + (size_t)(tokBase + stok) * cE + e0;
        const float* sp = sub  + (size_t)(tokBase + stok) * 384 + seg * 12;
        float4 vn = *(const float4*)np;
        float4 f0 = *(const float4*)(sp + 0);   // e0j0 e0j1 e0j2 e1j0
        float4 f1 = *(const float4*)(sp + 4);   // e1j1 e1j2 e2j0 e2j1
        float4 f2 = *(const float4*)(sp + 8);   // e2j2 e3j0 e3j1 e3j2
        *(ushort4*)&sA[(stok * cR) * PITCH + e0] =
            make_ushort4(f2bf(vn.x), f2bf(vn.y), f2bf(vn.z), f2bf(vn.w));
        *(ushort4*)&sA[(stok * cR + 1) * PITCH + e0] =
            make_ushort4(f2bf(f0.x), f2bf(f0.w), f2bf(f1.z), f2bf(f2.y));
        *(ushort4*)&sA[(stok * cR + 2) * PITCH + e0] =
            make_ushort4(f2bf(f0.y), f2bf(f1.x), f2bf(f1.w), f2bf(f2.z));
        *(ushort4*)&sA[(stok * cR + 3) * PITCH + e0] =
            make_ushort4(f2bf(f0.z), f2bf(f1.y), f2bf(f2.x), f2bf(f2.w));
    }
    __syncthreads();

    // ---- QKV GEMM: [64 rows x 16 f] per wave (head wv), 3 weights.
    f4v qa[4], ka[4], va[4];
    #pragma unroll
    for (int rt = 0; rt < 4; ++rt) {
        qa[rt] = (f4v){0.f, 0.f, 0.f, 0.f};
        ka[rt] = (f4v){0.f, 0.f, 0.f, 0.f};
        va[rt] = (f4v){0.f, 0.f, 0.f, 0.f};
    }
    #pragma unroll
    for (int kc = 0; kc < 4; ++kc) {
        const int koff = kc * 32 + lq * 8;
        s8v a0 = *(const s8v*)&sA[(0 * 16 + l15) * PITCH + koff];
        s8v a1 = *(const s8v*)&sA[(1 * 16 + l15) * PITCH + koff];
        s8v a2 = *(const s8v*)&sA[(2 * 16 + l15) * PITCH + koff];
        s8v a3 = *(const s8v*)&sA[(3 * 16 + l15) * PITCH + koff];
        const size_t fo = (size_t)(wv * 16 + l15) * cE + koff;
        s8v wq_ = *(const s8v*)(wqkv + fo);
        s8v wk_ = *(const s8v*)(wqkv + 16384 + fo);
        s8v wv_ = *(const s8v*)(wqkv + 32768 + fo);
        qa[0] = __builtin_amdgcn_mfma_f32_16x16x32_bf16(wq_, a0, qa[0], 0, 0, 0);
        qa[1] = __builtin_amdgcn_mfma_f32_16x16x32_bf16(wq_, a1, qa[1], 0, 0, 0);
        qa[2] = __builtin_amdgcn_mfma_f32_16x16x32_bf16(wq_, a2, qa[2], 0, 0, 0);
        qa[3] = __builtin_amdgcn_mfma_f32_16x16x32_bf16(wq_, a3, qa[3], 0, 0, 0);
        ka[0] = __builtin_amdgcn_mfma_f32_16x16x32_bf16(wk_, a0, ka[0], 0, 0, 0);
        ka[1] = __builtin_amdgcn_mfma_f32_16x16x32_bf16(wk_, a1, ka[1], 0, 0, 0);
        ka[2] = __builtin_amdgcn_mfma_f32_16x16x32_bf16(wk_, a2, ka[2], 0, 0, 0);
        ka[3] = __builtin_amdgcn_mfma_f32_16x16x32_bf16(wk_, a3, ka[3], 0, 0, 0);
        va[0] = __builtin_amdgcn_mfma_f32_16x16x32_bf16(wv_, a0, va[0], 0, 0, 0);
        va[1] = __builtin_amdgcn_mfma_f32_16x16x32_bf16(wv_, a1, va[1], 0, 0, 0);
        va[2] = __builtin_amdgcn_mfma_f32_16x16x32_bf16(wv_, a2, va[2], 0, 0, 0);
        va[3] = __builtin_amdgcn_mfma_f32_16x16x32_bf16(wv_, a3, va[3], 0, 0, 0);
    }
    // bias add (L1/L2-resident global reads)
    {
        const int fb = wv * 16 + lq * 4;
        float4 b0 = *(const float4*)(bqkv + fb);
        float4 b1 = *(const float4*)(bqkv + cE + fb);
        float4 b2 = *(const float4*)(bqkv + 2 * cE + fb);
        #pragma unroll
        for (int rt = 0; rt < 4; ++rt) {
            qa[rt][0] += b0.x; qa[rt][1] += b0.y;
            qa[rt][2] += b0.z; qa[rt][3] += b0.w;
            ka[rt][0] += b1.x; ka[rt][1] += b1.y;
            ka[rt][2] += b1.z; ka[rt][3] += b1.w;
            va[rt][0] += b2.x; va[rt][1] += b2.y;
            va[rt][2] += b2.z; va[rt][3] += b2.w;
        }
    }

    // ---- attention in registers -> oconcat (global, fire-and-forget)
    {
        const int r  = l15 & 3;
        const int tq = l15 >> 2;
        #pragma unroll
        for (int rt = 0; rt < 4; ++rt) {
            f4v q = qa[rt], k = ka[rt], v = va[rt];
            float s0 = QB(k[0],0x00)*q[0] + QB(k[1],0x00)*q[1]
                     + QB(k[2],0x00)*q[2] + QB(k[3],0x00)*q[3];
            float s1 = QB(k[0],0x55)*q[0] + QB(k[1],0x55)*q[1]
                     + QB(k[2],0x55)*q[2] + QB(k[3],0x55)*q[3];
            float s2 = QB(k[0],0xAA)*q[0] + QB(k[1],0xAA)*q[1]
                     + QB(k[2],0xAA)*q[2] + QB(k[3],0xAA)*q[3];
            float s3 = QB(k[0],0xFF)*q[0] + QB(k[1],0xFF)*q[1]
                     + QB(k[2],0xFF)*q[2] + QB(k[3],0xFF)*q[3];
            s0 += __shfl_xor(s0, 16); s0 += __shfl_xor(s0, 32);
            s1 += __shfl_xor(s1, 16); s1 += __shfl_xor(s1, 32);
            s2 += __shfl_xor(s2, 16); s2 += __shfl_xor(s2, 32);
            s3 += __shfl_xor(s3, 16); s3 += __shfl_xor(s3, 32);
            float m = fmaxf(fmaxf(s0, s1), fmaxf(s2, s3));
            float p0 = __expf(s0 - m), p1 = __expf(s1 - m);
            float p2 = __expf(s2 - m), p3 = __expf(s3 - m);
            float inv = 1.f / (p0 + p1 + p2 + p3);
            p0 *= inv; p1 *= inv; p2 *= inv; p3 *= inv;
            float o0 = p0*QB(v[0],0x00) + p1*QB(v[0],0x55)
                     + p2*QB(v[0],0xAA) + p3*QB(v[0],0xFF);
            float o1 = p0*QB(v[1],0x00) + p1*QB(v[1],0x55)
                     + p2*QB(v[1],0xAA) + p3*QB(v[1],0xFF);
            float o2 = p0*QB(v[2],0x00) + p1*QB(v[2],0x55)
                     + p2*QB(v[2],0xAA) + p3*QB(v[2],0xFF);
            float o3 = p0*QB(v[3],0x00) + p1*QB(v[3],0x55)
                     + p2*QB(v[3],0xAA) + p3*QB(v[3],0xFF);
            const int tok = tokBase + rt * 4 + tq;
            unsigned int u0 = (unsigned int)f2bf(o0) | ((unsigned int)f2bf(o1) << 16);
            unsigned int u1 = (unsigned int)f2bf(o2) | ((unsigned int)f2bf(o3) << 16);
            *(uint2*)&oconcat[(size_t)tok * 512 + r * cE + wv * 16 + lq * 4] =
                make_uint2(u0, u1);
        }
    }
}

// ---------------------------------------------------------------------------
// Kernel B: out[NT][128] = oconcat[NT][512] @ meff^T + beff.
// 64-token tiles (grid 1024), 256 thr / 4 waves, BK=64, canonical staging.
// meff read once per 64 tokens (4x less L2 weight traffic than the fused
// final GEMM); oconcat streams from LLC. Swapped-operand MFMA (r11-verified
// C mapping: col=l15 -> token, reg -> e1).
// ---------------------------------------------------------------------------
#define BPAD 72   // 64 + 8 pad elems; row stride 144B = 16B-aligned, 4-bank rot

__global__ __launch_bounds__(256) void k_gemmB(
    const unsigned short* __restrict__ oconcat,  // [NT][512] bf16
    const unsigned short* __restrict__ meff,     // [128][512] bf16 (B^T)
    const float* __restrict__ beff,              // [128]
    float* __restrict__ out)                     // [NT][128]
{
    __shared__ unsigned short sT[64 * BPAD];     // 9216 B

    const int tid  = threadIdx.x;
    const int lane = tid & 63;
    const int w    = tid >> 6;      // wave 0..3 -> e1 cols [w*32, w*32+32)
    const int l15  = lane & 15;
    const int lq   = lane >> 4;

    const int tokBase = blockIdx.x * 64;

    f4v acc[4][2];
    #pragma unroll
    for (int rt = 0; rt < 4; ++rt) {
        acc[rt][0] = (f4v){0.f, 0.f, 0.f, 0.f};
        acc[rt][1] = (f4v){0.f, 0.f, 0.f, 0.f};
    }

    #pragma clang loop unroll(disable)
    for (int ks = 0; ks < 8; ++ks) {
        __syncthreads();   // prev step's sT readers done
        // stage 64 tok x 64 k (16B per thread x 2 iters; 128B-contiguous rows)
        #pragma unroll
        for (int it = 0; it < 2; ++it) {
            const int row = it * 32 + (tid >> 3);
            const int ko  = (tid & 7) * 8;
            *(uint4*)&sT[row * BPAD + ko] =
                *(const uint4*)&oconcat[(size_t)(tokBase + row) * 512 + ks * 64 + ko];
        }
        __syncthreads();
        #pragma unroll
        for (int kh = 0; kh < 2; ++kh) {
            const int ko = kh * 32 + lq * 8;
            s8v b0 = *(const s8v*)(meff + (size_t)(w * 32 + l15)      * 512 + ks * 64 + ko);
            s8v b1 = *(const s8v*)(meff + (size_t)(w * 32 + 16 + l15) * 512 + ks * 64 + ko);
            #pragma unroll
            for (int rt = 0; rt < 4; ++rt) {
                s8v a = *(const s8v*)&sT[(rt * 16 + l15) * BPAD + ko];
                acc[rt][0] = __builtin_amdgcn_mfma_f32_16x16x32_bf16(b0, a, acc[rt][0], 0, 0, 0);
                acc[rt][1] = __builtin_amdgcn_mfma_f32_16x16x32_bf16(b1, a, acc[rt][1], 0, 0, 0);
            }
        }
    }
    // epilogue: C col=l15 -> token, reg i -> e1 = w*32 + cc*16 + lq*4 + i
    #pragma unroll
    for (int cc = 0; cc < 2; ++cc) {
        const int col = w * 32 + cc * 16 + lq * 4;
        float4 b4 = *(const float4*)&beff[col];
        #pragma unroll
        for (int rt = 0; rt < 4; ++rt) {
            *(float4*)&out[(size_t)(tokBase + rt * 16 + l15) * cE + col] =
                make_float4(acc[rt][cc][0] + b4.x, acc[rt][cc][1] + b4.y,
                            acc[rt][cc][2] + b4.z, acc[rt][cc][3] + b4.w);
        }
    }
}

// ---------------------------------------------------------------------------
// Fallback: r11 monolith (162.8us), used only if ws_size can't hold oconcat.
// ---------------------------------------------------------------------------
#define TOKBF  64
__global__ __launch_bounds__(512) void k_mainR11(
    const float* __restrict__ node, const float* __restrict__ sub,
    const unsigned short* __restrict__ wqkv,
    const unsigned short* __restrict__ meff,
    const float* __restrict__ bqkv,
    const float* __restrict__ beff,
    float* __restrict__ out)
{
    __shared__ unsigned short sA[64 * PITCH];
    __shared__ unsigned short sO[16 * OPITCH];

    const int tid  = threadIdx.x;
    const int lane = tid & 63;
    const int wv   = tid >> 6;
    const int l15  = lane & 15;
    const int lq   = lane >> 4;

    const int tokBlock = blockIdx.x * TOKBF;
    const int stok = tid >> 5;
    const int seg  = tid & 31;
    const int e0   = seg * 4;

    #pragma clang loop unroll(disable)
    for (int chunk = 0; chunk < TOKBF / TOKC; ++chunk) {
        const int tokBase = tokBlock + chunk * TOKC;
        __syncthreads();
        {
            const float* np = node + (size_t)(tokBase + stok) * cE + e0;
            const float* sp = sub  + (size_t)(tokBase + stok) * 384 + seg * 12;
            float4 vn = *(const float4*)np;
            float4 f0 = *(const float4*)(sp + 0);
            float4 f1 = *(const float4*)(sp + 4);
            float4 f2 = *(const float4*)(sp + 8);
            *(ushort4*)&sA[(stok * cR) * PITCH + e0] =
                make_ushort4(f2bf(vn.x), f2bf(vn.y), f2bf(vn.z), f2bf(vn.w));
            *(ushort4*)&sA[(stok * cR + 1) * PITCH + e0] =
                make_ushort4(f2bf(f0.x), f2bf(f0.w), f2bf(f1.z), f2bf(f2.y));
            *(ushort4*)&sA[(stok * cR + 2) * PITCH + e0] =
                make_ushort4(f2bf(f0.y), f2bf(f1.x), f2bf(f1.w), f2bf(f2.z));
            *(ushort4*)&sA[(stok * cR + 3) * PITCH + e0] =
                make_ushort4(f2bf(f0.z), f2bf(f1.y), f2bf(f2.x), f2bf(f2.w));
        }
        __syncthreads();

        f4v qa[4], ka[4], va[4];
        #pragma unroll
        for (int rt = 0; rt < 4; ++rt) {
            qa[rt] = (f4v){0.f, 0.f, 0.f, 0.f};
            ka[rt] = (f4v){0.f, 0.f, 0.f, 0.f};
            va[rt] = (f4v){0.f, 0.f, 0.f, 0.f};
        }
        #pragma unroll
        for (int kc = 0; kc < 4; ++kc) {
            const int koff = kc * 32 + lq * 8;
            s8v a0 = *(const s8v*)&sA[(0 * 16 + l15) * PITCH + koff];
            s8v a1 = *(const s8v*)&sA[(1 * 16 + l15) * PITCH + koff];
            s8v a2 = *(const s8v*)&sA[(2 * 16 + l15) * PITCH + koff];
            s8v a3 = *(const s8v*)&sA[(3 * 16 + l15) * PITCH + koff];
            const size_t fo = (size_t)(wv * 16 + l15) * cE + koff;
            s8v wq_ = *(const s8v*)(wqkv + fo);
            s8v wk_ = *(const s8v*)(wqkv + 16384 + fo);
            s8v wv_ = *(const s8v*)(wqkv + 32768 + fo);
            qa[0] = __builtin_amdgcn_mfma_f32_16x16x32_bf16(wq_, a0, qa[0], 0, 0, 0);
            qa[1] = __builtin_amdgcn_mfma_f32_16x16x32_bf16(wq_, a1, qa[1], 0, 0, 0);
            qa[2] = __builtin_amdgcn_mfma_f32_16x16x32_bf16(wq_, a2, qa[2], 0, 0, 0);
            qa[3] = __builtin_amdgcn_mfma_f32_16x16x32_bf16(wq_, a3, qa[3], 0, 0, 0);
            ka[0] = __builtin_amdgcn_mfma_f32_16x16x32_bf16(wk_, a0, ka[0], 0, 0, 0);
            ka[1] = __builtin_amdgcn_mfma_f32_16x16x32_bf16(wk_, a1, ka[1], 0, 0, 0);
            ka[2] = __builtin_amdgcn_mfma_f32_16x16x32_bf16(wk_, a2, ka[2], 0, 0, 0);
            ka[3] = __builtin_amdgcn_mfma_f32_16x16x32_bf16(wk_, a3, ka[3], 0, 0, 0);
            va[0] = __builtin_amdgcn_mfma_f32_16x16x32_bf16(wv_, a0, va[0], 0, 0, 0);
            va[1] = __builtin_amdgcn_mfma_f32_16x16x32_bf16(wv_, a1, va[1], 0, 0, 0);
            va[2] = __builtin_amdgcn_mfma_f32_16x16x32_bf16(wv_, a2, va[2], 0, 0, 0);
            va[3] = __builtin_amdgcn_mfma_f32_16x16x32_bf16(wv_, a3, va[3], 0, 0, 0);
        }
        {
            const int fb = wv * 16 + lq * 4;
            float4 b0 = *(const float4*)(bqkv + fb);
            float4 b1 = *(const float4*)(bqkv + cE + fb);
            float4 b2 = *(const float4*)(bqkv + 2 * cE + fb);
            #pragma unroll
            for (int rt = 0; rt < 4; ++rt) {
                qa[rt][0] += b0.x; qa[rt][1] += b0.y;
                qa[rt][2] += b0.z; qa[rt][3] += b0.w;
                ka[rt][0] += b1.x; ka[rt][1] += b1.y;
                ka[rt][2] += b1.z; ka[rt][3] += b1.w;
                va[rt][0] += b2.x; va[rt][1] += b2.y;
                va[rt][2] += b2.z; va[rt][3] += b2.w;
            }
        }
        {
            const int r  = l15 & 3;
            const int tq = l15 >> 2;
            #pragma unroll
            for (int rt = 0; rt < 4; ++rt) {
                f4v q = qa[rt], k = ka[rt], v = va[rt];
                float s0 = QB(k[0],0x00)*q[0] + QB(k[1],0x00)*q[1]
                         + QB(k[2],0x00)*q[2] + QB(k[3],0x00)*q[3];
                float s1 = QB(k[0],0x55)*q[0] + QB(k[1],0x55)*q[1]
                         + QB(k[2],0x55)*q[2] + QB(k[3],0x55)*q[3];
                float s2 = QB(k[0],0xAA)*q[0] + QB(k[1],0xAA)*q[1]
                         + QB(k[2],0xAA)*q[2] + QB(k[3],0xAA)*q[3];
                float s3 = QB(k[0],0xFF)*q[0] + QB(k[1],0xFF)*q[1]
                         + QB(k[2],0xFF)*q[2] + QB(k[3],0xFF)*q[3];
                s0 += __shfl_xor(s0, 16); s0 += __shfl_xor(s0, 32);
                s1 += __shfl_xor(s1, 16); s1 += __shfl_xor(s1, 32);
                s2 += __shfl_xor(s2, 16); s2 += __shfl_xor(s2, 32);
                s3 += __shfl_xor(s3, 16); s3 += __shfl_xor(s3, 32);
                float m = fmaxf(fmaxf(s0, s1), fmaxf(s2, s3));
                float p0 = __expf(s0 - m), p1 = __expf(s1 - m);
                float p2 = __expf(s2 - m), p3 = __expf(s3 - m);
                float inv = 1.f / (p0 + p1 + p2 + p3);
                p0 *= inv; p1 *= inv; p2 *= inv; p3 *= inv;
                float o0 = p0*QB(v[0],0x00) + p1*QB(v[0],0x55)
                         + p2*QB(v[0],0xAA) + p3*QB(v[0],0xFF);
                float o1 = p0*QB(v[1],0x00) + p1*QB(v[1],0x55)
                         + p2*QB(v[1],0xAA) + p3*QB(v[1],0xFF);
                float o2 = p0*QB(v[2],0x00) + p1*QB(v[2],0x55)
                         + p2*QB(v[2],0xAA) + p3*QB(v[2],0xFF);
                float o3 = p0*QB(v[3],0x00) + p1*QB(v[3],0x55)
                         + p2*QB(v[3],0xAA) + p3*QB(v[3],0xFF);
                int tok = rt * 4 + tq;
                *(ushort4*)&sO[tok * OPITCH + r * cE + wv * 16 + lq * 4] =
                    make_ushort4(f2bf(o0), f2bf(o1), f2bf(o2), f2bf(o3));
            }
        }
        __syncthreads();
        {
            f4v acc = (f4v){0.f, 0.f, 0.f, 0.f};
            #pragma unroll 4
            for (int kc = 0; kc < 16; ++kc) {
                int koff = kc * 32 + lq * 8;
                s8v a = *(const s8v*)&sO[l15 * OPITCH + koff];
                s8v b = *(const s8v*)(meff + (size_t)(wv * 16 + l15) * 512 + koff);
                acc = __builtin_amdgcn_mfma_f32_16x16x32_bf16(b, a, acc, 0, 0, 0);
            }
            const int col = wv * 16 + lq * 4;
            float4 b4 = *(const float4*)&beff[col];
            *(float4*)&out[(size_t)(tokBase + l15) * cE + col] =
                make_float4(acc[0] + b4.x, acc[1] + b4.y,
                            acc[2] + b4.z, acc[3] + b4.w);
        }
    }
}

// ---------------------------------------------------------------------------
extern "C" void kernel_launch(void* const* d_in, const int* in_sizes, int n_in,
                              void* d_out, int out_size, void* d_ws, size_t ws_size,
                              hipStream_t stream) {
    const float* node  = (const float*)d_in[0];
    const float* sub   = (const float*)d_in[1];
    const float* Wq    = (const float*)d_in[2];
    const float* bq    = (const float*)d_in[3];
    const float* Wk    = (const float*)d_in[4];
    const float* bk    = (const float*)d_in[5];
    const float* Wv    = (const float*)d_in[6];
    const float* bv    = (const float*)d_in[7];
    const float* in_w  = (const float*)d_in[8];
    const float* in_b  = (const float*)d_in[9];
    const float* out_w = (const float*)d_in[10];
    const float* out_b = (const float*)d_in[11];
    const float* fc_w  = (const float*)d_in[12];
    const float* fc_b  = (const float*)d_in[13];

    unsigned short* ws_wqkv = (unsigned short*)d_ws;                 // 3*128*128 bf16
    unsigned short* ws_meff = ws_wqkv + 3 * cE * cE;                 // 128*512  bf16
    float* ws_bqkv = (float*)((char*)d_ws + (size_t)(3 * cE * cE + cE * cR * cE) * 2);
    float* ws_beff = ws_bqkv + 3 * cE;

    k_prep<<<dim3(1794), dim3(256), 0, stream>>>(Wq, Wk, Wv, in_w, out_w, fc_w,
                                                 bq, bk, bv, in_b, out_b, fc_b,
                                                 ws_wqkv, ws_meff, ws_bqkv, ws_beff);

    const size_t oofs = (size_t)1 << 20;                 // 1 MB, past weights
    const size_t need = oofs + (size_t)cNT * 512 * 2;    // + 64 MB oconcat
    if (ws_size >= need) {
        unsigned short* oconcat = (unsigned short*)((char*)d_ws + oofs);
        k_mainA<<<dim3(cNT / TOKC), dim3(512), 0, stream>>>(
            node, sub, ws_wqkv, ws_bqkv, oconcat);
        k_gemmB<<<dim3(cNT / 64), dim3(256), 0, stream>>>(
            oconcat, ws_meff, ws_beff, (float*)d_out);
    } else {
        k_mainR11<<<dim3(cNT / TOKBF), dim3(512), 0, stream>>>(
            node, sub, ws_wqkv, ws_meff, ws_bqkv, ws_beff, (float*)d_out);
    }
}